// Round 9
// baseline (61.908 us; speedup 1.0000x reference)
//
#include <hip/hip_runtime.h>
#include <cstdint>
#include <cstddef>

#define BATCH 64
#define PRI   8732
#define NCLS  81
#define NEGPOS 3
#define NTOT  (BATCH * PRI)          // 558848
#define PW    16                     // priors per wave-window
#define NWINW (NTOT / PW)            // 34928 wave-windows
#define WB_F  (PW * NCLS)            // 1296 floats per wave-window
#define WB_F4 (WB_F / 4)             // 324 float4
#define NBLK  512                    // 2 blocks/CU (62 KB LDS each)
#define WAVES_TOT (NBLK * 4)         // 2048 wave pipelines

__device__ __forceinline__ unsigned keymap(float f) {
    unsigned u = __float_as_uint(f);
    return (u & 0x80000000u) ? ~u : (u | 0x80000000u);
}

__device__ __forceinline__ void gl_lds16(const float4* g, float4* l) {
    __builtin_amdgcn_global_load_lds(
        (const __attribute__((address_space(1))) void*)(const void*)g,
        (__attribute__((address_space(3))) void*)(void*)l, 16, 0, 0);
}

// ---------------------------------------------------------------------------
// Kernel 1: barrier-free per-wave pipeline. 512 blocks x 256 thr; each WAVE
// owns windows ww = wgl + i*2048 (16 priors, 5.2 KB) in a private triple
// buffer. Steady state: stage(i+1), stage(i+2) in flight; exact counted
// s_waitcnt vmcnt(N) is the only synchronization (no __syncthreads at all).
// Pure stream: 6 gl_lds + 1 key-store per iteration per wave — no labels,
// no conditional vmem (positive-prior work moved to k_row).
// Compute: 4 lanes/prior, aligned ds_read_b128, -inf edge masks, 2-shfl merge.
// ---------------------------------------------------------------------------
__global__ __launch_bounds__(256) void k_lse(const float* __restrict__ conf,
                                             unsigned* __restrict__ keysg) {
    __shared__ float lds[4][3][WB_F];            // 62208 B
    const int t = threadIdx.x, wid = t >> 6, lane = t & 63;
    const int wgl = blockIdx.x * 4 + wid;        // 0..2047
    const float4* conf4 = reinterpret_cast<const float4*>(conf);

    auto stage = [&](int b, int w) {             // 6 vmem instrs per wave
        const float4* g4 = conf4 + (size_t)w * WB_F4;
        float4* l4 = reinterpret_cast<float4*>(&lds[wid][b][0]);
#pragma unroll
        for (int j = 0; j < 5; ++j) gl_lds16(&g4[j * 64 + lane], &l4[j * 64 + lane]);
        if (lane < 4) gl_lds16(&g4[320 + lane], &l4[320 + lane]);
    };

    // prologue: every wave has >= 17 windows, both stages valid
    stage(0, wgl);
    stage(1, wgl + WAVES_TOT);

    int b = 0;
    int w = wgl;
    for (int i = 0; ; ++i, w += WAVES_TOT) {
        const int wn1 = w + WAVES_TOT;
        const int wn2 = w + 2 * WAVES_TOT;
        // exact counted waits: stage(i) must be retired (in-order vmcnt).
        if (i == 0)            asm volatile("s_waitcnt vmcnt(6)" ::: "memory");
        else if (wn1 < NWINW)  asm volatile("s_waitcnt vmcnt(7)" ::: "memory");
        else                   asm volatile("s_waitcnt vmcnt(1)" ::: "memory");
        __builtin_amdgcn_sched_barrier(0);
        if (wn2 < NWINW) stage((b == 0) ? 2 : b - 1, wn2);   // (b+2)%3

        // ---- compute window w from lds[wid][b]
        const float* B = &lds[wid][b][0];
        const int q  = lane >> 2, h = lane & 3;
        const int f0 = q * NCLS + 20 * h;
        const int len = (h == 3) ? 21 : 20;
        const int a0 = f0 & ~3;
        const int o  = f0 & 3;
        const int ve = o + len;

        const float4* lp = reinterpret_cast<const float4*>(B + a0);
        float4 v0 = lp[0], v1 = lp[1], v2 = lp[2], v3 = lp[3], v4 = lp[4], v5 = lp[5];
        v0.x = (o > 0) ? -INFINITY : v0.x;
        v0.y = (o > 1) ? -INFINITY : v0.y;
        v0.z = (o > 2) ? -INFINITY : v0.z;
        v5.x = (ve > 20) ? v5.x : -INFINITY;
        v5.y = (ve > 21) ? v5.y : -INFINITY;
        v5.z = (ve > 22) ? v5.z : -INFINITY;
        v5.w = (ve > 23) ? v5.w : -INFINITY;

        float m;
        {
            float a = fmaxf(fmaxf(v0.x, v0.y), fmaxf(v0.z, v0.w));
            float c = fmaxf(fmaxf(v1.x, v1.y), fmaxf(v1.z, v1.w));
            float d = fmaxf(fmaxf(v2.x, v2.y), fmaxf(v2.z, v2.w));
            float e = fmaxf(fmaxf(v3.x, v3.y), fmaxf(v3.z, v3.w));
            float f = fmaxf(fmaxf(v4.x, v4.y), fmaxf(v4.z, v4.w));
            float g = fmaxf(fmaxf(v5.x, v5.y), fmaxf(v5.z, v5.w));
            m = fmaxf(fmaxf(fmaxf(a, c), fmaxf(d, e)), fmaxf(f, g));
        }
        float s =
            __expf(v0.x - m) + __expf(v0.y - m) + __expf(v0.z - m) + __expf(v0.w - m) +
            __expf(v1.x - m) + __expf(v1.y - m) + __expf(v1.z - m) + __expf(v1.w - m) +
            __expf(v2.x - m) + __expf(v2.y - m) + __expf(v2.z - m) + __expf(v2.w - m) +
            __expf(v3.x - m) + __expf(v3.y - m) + __expf(v3.z - m) + __expf(v3.w - m) +
            __expf(v4.x - m) + __expf(v4.y - m) + __expf(v4.z - m) + __expf(v4.w - m) +
            __expf(v5.x - m) + __expf(v5.y - m) + __expf(v5.z - m) + __expf(v5.w - m);

#pragma unroll
        for (int off = 1; off <= 2; off <<= 1) {
            const float mo = __shfl_xor(m, off, 64);
            const float so = __shfl_xor(s, off, 64);
            const float mn = fmaxf(m, mo);
            s = s * __expf(m - mn) + so * __expf(mo - mn);
            m = mn;
        }
        const float lse = m + __logf(s);

        if (h == 0) {                             // 1 vmem store per wave
            const float c0 = B[q * NCLS];
            keysg[(size_t)w * PW + q] = keymap(lse - c0);   // bg >= 0
        }

        b = (b == 2) ? 0 : b + 1;
        if (wn1 >= NWINW) break;
    }
}

// ---------------------------------------------------------------------------
// Kernel 2: one block (1024 thr) per batch row. Loop A: stream labels+keys,
// zero positive keys, count positives. Radix select (R6-exact: wave-private
// hists, plain atomics, suffix-scan). Selected-negative sum from keys.
// Loop B: gather pass for positives (ce = bg + c0 - c_lab via L3-resident
// conf; smooth-L1 from ploc/gloc). Writes per-row partials.
// ---------------------------------------------------------------------------
__global__ __launch_bounds__(1024) void k_row(const unsigned* __restrict__ keysg,
                                              const int* __restrict__ labels,
                                              const float* __restrict__ conf,
                                              const float* __restrict__ ploc,
                                              const float* __restrict__ gloc,
                                              float* __restrict__ rowobj,
                                              float* __restrict__ rowsl,
                                              float* __restrict__ rownp) {
    __shared__ unsigned keys_s[PRI];            // 34928 B
    __shared__ unsigned hist[16][257];          // wave-private, padded
    __shared__ unsigned ured[16];
    __shared__ float    fred[16], fred2[16];
    __shared__ unsigned sh_prefix, sh_r;
    __shared__ int      sh_flag;

    const int row  = blockIdx.x;
    const int tid  = threadIdx.x;
    const int wid  = tid >> 6;
    const int lane = tid & 63;
    const unsigned* krow    = keysg  + (size_t)row * PRI;
    const int*      lab_row = labels + (size_t)row * PRI;

    // ---- loop A: stage keys (positives -> 0) + count positives
    unsigned np = 0;
    for (int j = tid; j < PRI; j += 1024) {
        const int lab = lab_row[j];
        const unsigned key = krow[j];
        const bool pos = (lab > 0);
        np += pos ? 1u : 0u;
        keys_s[j] = pos ? 0u : key;
    }
#pragma unroll
    for (int off = 32; off > 0; off >>= 1) np += __shfl_xor(np, off, 64);
    if (lane == 0) ured[wid] = np;
    __syncthreads();
    unsigned num_pos = 0;
#pragma unroll
    for (int w = 0; w < 16; ++w) num_pos += ured[w];
    const int k = (int)num_pos * NEGPOS;

    // ---- exact radix select (k-th largest negative key), R6-identical
    unsigned Kstar = 0xFFFFFFFFu;
    int r_eq = 0;
    bool take_all = false;
    if (k > 0) {
        unsigned prefix = 0;
        int r = k, flag = 0;
        unsigned* hist_flat = &hist[0][0];
        for (int level = 3; level >= 0; --level) {
            const int shift = level * 8;
            for (int i = tid; i < 16 * 257; i += 1024) hist_flat[i] = 0;
            __syncthreads();
            for (int j = tid; j < PRI; j += 1024) {
                const unsigned key = keys_s[j];
                if (key == 0u) continue;
                if (level < 3 && (key >> (shift + 8)) != (prefix >> (shift + 8))) continue;
                atomicAdd(&hist[wid][(key >> shift) & 255u], 1u);
            }
            __syncthreads();
            if (wid == 0) {
                const int b0 = lane * 4;
                unsigned h0 = 0, h1 = 0, h2 = 0, h3 = 0;
#pragma unroll
                for (int w = 0; w < 16; ++w) {
                    h0 += hist[w][b0]; h1 += hist[w][b0 + 1];
                    h2 += hist[w][b0 + 2]; h3 += hist[w][b0 + 3];
                }
                const unsigned loc = h0 + h1 + h2 + h3;
                unsigned ssum = loc;                  // inclusive suffix scan
#pragma unroll
                for (int o2 = 1; o2 < 64; o2 <<= 1) {
                    const unsigned t2 = __shfl_down(ssum, o2, 64);
                    if (lane + o2 < 64) ssum += t2;
                }
                const unsigned above = ssum - loc;
                const unsigned cum3 = above + h3;
                const unsigned cum2 = cum3 + h2;
                const unsigned cum1 = cum2 + h1;
                const unsigned cum0 = cum1 + h0;
                const unsigned long long msk = __ballot(cum0 >= (unsigned)r);
                if (msk == 0ULL) {
                    if (lane == 0) sh_flag = 1;       // fewer negatives than k
                } else {
                    const int L = 63 - __clzll(msk);
                    if (lane == L) {
                        unsigned selbin, cumsel, hsel;
                        if      (cum3 >= (unsigned)r) { selbin = b0 + 3; cumsel = cum3; hsel = h3; }
                        else if (cum2 >= (unsigned)r) { selbin = b0 + 2; cumsel = cum2; hsel = h2; }
                        else if (cum1 >= (unsigned)r) { selbin = b0 + 1; cumsel = cum1; hsel = h1; }
                        else                          { selbin = b0;     cumsel = cum0; hsel = h0; }
                        sh_prefix = prefix | (selbin << shift);
                        sh_r = (unsigned)r - (cumsel - hsel);
                        sh_flag = 0;
                    }
                }
            }
            __syncthreads();
            flag = sh_flag;
            if (flag) break;
            prefix = sh_prefix;
            r = (int)sh_r;
        }
        take_all = (flag != 0);
        if (!take_all) { Kstar = prefix; r_eq = r; }
    }

    // ---- selected-negative sum (ce == bg for negatives)
    float obj = 0.0f;
    if (k > 0) {
        for (int j = tid; j < PRI; j += 1024) {
            const unsigned key = keys_s[j];
            if (key != 0u && (take_all || key > Kstar))
                obj += __uint_as_float(key ^ 0x80000000u);
        }
        if (tid == 0 && !take_all)
            obj += (float)r_eq * __uint_as_float(Kstar ^ 0x80000000u);
    }

    // ---- loop B: positive gathers (conf row is L3-resident after k_lse)
    float sl = 0.0f;
    for (int s2 = 0; s2 < 9; ++s2) {
        const int j = tid * 9 + s2;
        if (j >= PRI) break;
        const int lab = lab_row[j];
        if (lab > 0) {
            const size_t p = (size_t)row * PRI + j;
            const float bg = __uint_as_float(krow[j] ^ 0x80000000u);
            const float c0 = conf[p * NCLS];
            const float cl = conf[p * NCLS + (size_t)lab];
            obj += bg + c0 - cl;                 // ce = lse - c_lab
            const float4 pl = *reinterpret_cast<const float4*>(ploc + p * 4);
            const float4 gl = *reinterpret_cast<const float4*>(gloc + p * 4);
            float d, a;
            d = pl.x - gl.x; a = fabsf(d); sl += (a < 1.0f) ? 0.5f * d * d : a - 0.5f;
            d = pl.y - gl.y; a = fabsf(d); sl += (a < 1.0f) ? 0.5f * d * d : a - 0.5f;
            d = pl.z - gl.z; a = fabsf(d); sl += (a < 1.0f) ? 0.5f * d * d : a - 0.5f;
            d = pl.w - gl.w; a = fabsf(d); sl += (a < 1.0f) ? 0.5f * d * d : a - 0.5f;
        }
    }

    // ---- block reduce, write per-row results
#pragma unroll
    for (int off = 32; off > 0; off >>= 1) {
        obj += __shfl_xor(obj, off, 64);
        sl  += __shfl_xor(sl,  off, 64);
    }
    __syncthreads();
    if (lane == 0) { fred[wid] = obj; fred2[wid] = sl; }
    __syncthreads();
    if (tid == 0) {
        float to = 0.0f, ts = 0.0f;
#pragma unroll
        for (int w = 0; w < 16; ++w) { to += fred[w]; ts += fred2[w]; }
        rowobj[row] = to;
        rowsl[row]  = ts;
        rownp[row]  = (float)num_pos;
    }
}

// ---------------------------------------------------------------------------
// Kernel 3: final reduction, one wave
// ---------------------------------------------------------------------------
__global__ __launch_bounds__(64) void k_final(const float* __restrict__ rowobj,
                                              const float* __restrict__ rowsl,
                                              const float* __restrict__ rownp,
                                              float* __restrict__ out) {
    const int lane = threadIdx.x;
    float o = rowobj[lane], s = rowsl[lane], n = rownp[lane];
#pragma unroll
    for (int off = 32; off > 0; off >>= 1) {
        o += __shfl_xor(o, off, 64);
        s += __shfl_xor(s, off, 64);
        n += __shfl_xor(n, off, 64);
    }
    if (lane == 0) {
        const float npos = fmaxf(n, 1.0f);
        out[0] = o / npos;
        out[1] = s / npos;
    }
}

extern "C" void kernel_launch(void* const* d_in, const int* in_sizes, int n_in,
                              void* d_out, int out_size, void* d_ws, size_t ws_size,
                              hipStream_t stream) {
    const float* pred_loc  = (const float*)d_in[0];
    const float* pred_conf = (const float*)d_in[1];
    const float* gt_loc    = (const float*)d_in[2];
    const int*   gt_labels = (const int*)d_in[3];
    float* out = (float*)d_out;

    unsigned* keysg  = (unsigned*)d_ws;                   // NTOT u32
    float*    rowobj = (float*)(keysg + NTOT);            // BATCH f
    float*    rowsl  = rowobj + BATCH;                    // BATCH f
    float*    rownp  = rowsl + BATCH;                     // BATCH f

    k_lse<<<NBLK, 256, 0, stream>>>(pred_conf, keysg);
    k_row<<<BATCH, 1024, 0, stream>>>(keysg, gt_labels, pred_conf,
                                      pred_loc, gt_loc, rowobj, rowsl, rownp);
    k_final<<<1, 64, 0, stream>>>(rowobj, rowsl, rownp, out);
}